// Round 9
// baseline (354.711 us; speedup 1.0000x reference)
//
#include <hip/hip_runtime.h>
#include <hip/hip_bf16.h>

typedef __bf16 bf16_t;
typedef bf16_t bf16x8 __attribute__((ext_vector_type(8)));
typedef bf16_t bf16x4 __attribute__((ext_vector_type(4)));
typedef float f32x4 __attribute__((ext_vector_type(4)));

typedef __attribute__((address_space(1))) const void gconst_void;
typedef __attribute__((address_space(3))) void lds_void;

__device__ __forceinline__ void async16(const bf16_t* g, bf16_t* l) {
  __builtin_amdgcn_global_load_lds((gconst_void*)g, (lds_void*)l, 16, 0, 0);
}

// ---- batched f32 -> bf16 conversion ----
struct CvtDesc { const float* src; bf16_t* dst; long n; };
struct CvtArgs { CvtDesc d[10]; };

__global__ __launch_bounds__(256) void cvt_many(CvtArgs a) {
  const CvtDesc de = a.d[blockIdx.y];
  long i = ((long)blockIdx.x * 256 + threadIdx.x) * 4;
  const long stride = (long)gridDim.x * 256 * 4;
  for (; i < de.n; i += stride) {
    float4 v = *(const float4*)(de.src + i);
    bf16x4 o;
    o[0] = (bf16_t)v.x; o[1] = (bf16_t)v.y; o[2] = (bf16_t)v.z; o[3] = (bf16_t)v.w;
    *(bf16x4*)(de.dst + i) = o;
  }
}

// ---- grouped GEMM: C[4096,N] = act(A[4096,K] @ W[N,K]^T + bias) ----
// Tile 128xBN (BN=64 or 128), 4 waves in 2x2, each wave owns 64x(BN/2).
// Depth-3 pipeline, SINGLE barrier per K-step:
//   wait vmcnt(LPS)  -> own stage(s) landed (stage(s+1) stays in flight)
//   barrier          -> all waves: compute(s-1) done AND stage(s) landed
//   stage(s+2)       -> overwrites buf[(s-1)%3]; safe (reads done at barrier)
//   compute(s)       -> reads buf[s%3]; safe (writes landed at barrier)
// M fixed 4096 (32 row-tiles), N mult of BN, K mult of 32 (>=4 steps).
// act: 0=none 1=relu 2=sigmoid. Up to 2 independent problems per launch.
struct GDesc {
  const bf16_t* A; const bf16_t* W; const float* bias; void* C;
  int N, K, act;
};
struct GArgs { GDesc d[2]; int ntiles0; };

template <typename OutT, bool MINMAX, int BN>
__global__ __launch_bounds__(256) void gemm_gb(GArgs ga, float* __restrict__ pmin,
                                               float* __restrict__ pmax) {
  constexpr int NJ = BN / 32;        // B-frags per wave (wave owns BN/2 cols)
  const int b = blockIdx.x;
  const int p = (b >= ga.ntiles0) ? 1 : 0;
  const GDesc d = ga.d[p];
  const int local = b - (p ? ga.ntiles0 : 0);
  const int bm = (local & 31) * 128;   // 32 row tiles (M=4096)
  const int bn = (local >> 5) * BN;
  const int N = d.N, K = d.K;

  // triple-buffered LDS tiles: BN=64 -> 36 KB, BN=128 -> 48 KB
  __shared__ __align__(16) bf16_t As[3][128 * 32];
  __shared__ __align__(16) bf16_t Bs[3][BN * 32];

  const int t = threadIdx.x;
  const int wave = t >> 6;
  const int lane = t & 63;
  const int quad = lane >> 4;
  const int l15 = lane & 15;
  const int wm = (wave >> 1) * 64;        // waves 2M x 2N
  const int wn = (wave & 1) * (BN / 2);

  f32x4 acc[4][NJ];
#pragma unroll
  for (int i = 0; i < 4; ++i)
#pragma unroll
    for (int j = 0; j < NJ; ++j) acc[i][j] = (f32x4){0.f, 0.f, 0.f, 0.f};

  // Staging swizzle: LDS slot s of row r holds global k-chunk (s-r-(r>>2))&3;
  // reader (quad q) uses slot (q+r+(r>>2))&3 (2-way worst-case aliasing).
  const int c0 = t, c1 = t + 256;
  const int r0 = c0 >> 2, kc0 = ((c0 & 3) - r0 - (r0 >> 2)) & 3;
  const int r1 = c1 >> 2, kc1 = ((c1 & 3) - r1 - (r1 >> 2)) & 3;
  const bf16_t* pa0 = d.A + (long)(bm + r0) * K + kc0 * 8;
  const bf16_t* pa1 = d.A + (long)(bm + r1) * K + kc1 * 8;
  const bf16_t* pw0 = d.W + (long)(bn + r0) * K + kc0 * 8;
  const bf16_t* pw1 = d.W + (long)(bn + r1) * K + kc1 * 8;  // BN=128 only
  bf16_t* lA0 = &As[0][c0 * 8]; bf16_t* lA1 = &As[0][c1 * 8];
  bf16_t* lB0 = &Bs[0][c0 * 8]; bf16_t* lB1 = &Bs[0][c1 * 8];
  const int bufOffA = 128 * 32;
  const int bufOffB = BN * 32;

  auto stage = [&](int ke, int bi) {
    const int oA = bi * bufOffA, oB = bi * bufOffB;
    async16(pa0 + ke, lA0 + oA);
    async16(pa1 + ke, lA1 + oA);
    async16(pw0 + ke, lB0 + oB);
    if constexpr (BN == 128) async16(pw1 + ke, lB1 + oB);
  };

  auto compute = [&](int bi) {
    const bf16_t* as = As[bi];
    const bf16_t* bs = Bs[bi];
    bf16x8 af[4], bfr[NJ];
#pragma unroll
    for (int i = 0; i < 4; ++i) {
      const int r = wm + i * 16 + l15;
      af[i] = *(const bf16x8*)&as[r * 32 + ((quad + r + (r >> 2)) & 3) * 8];
    }
#pragma unroll
    for (int j = 0; j < NJ; ++j) {
      const int r = wn + j * 16 + l15;
      bfr[j] = *(const bf16x8*)&bs[r * 32 + ((quad + r + (r >> 2)) & 3) * 8];
    }
    // Swapped operand order: register quad holds 4 consecutive output cols.
#pragma unroll
    for (int i = 0; i < 4; ++i)
#pragma unroll
      for (int j = 0; j < NJ; ++j)
        acc[i][j] = __builtin_amdgcn_mfma_f32_16x16x32_bf16(bfr[j], af[i],
                                                            acc[i][j], 0, 0, 0);
  };

  const int nsteps = K >> 5;
  stage(0, 0);
  stage(32, 1);
  for (int s = 0; s < nsteps; ++s) {
    // wait: own stage(s) landed. Steady state leaves stage(s+1) in flight
    // (LPS loads); last step drains everything.
    if (s == nsteps - 1) {
      asm volatile("s_waitcnt vmcnt(0)" ::: "memory");
    } else {
      if constexpr (BN == 128)
        asm volatile("s_waitcnt vmcnt(4)" ::: "memory");
      else
        asm volatile("s_waitcnt vmcnt(3)" ::: "memory");
    }
    __builtin_amdgcn_s_barrier();
    __builtin_amdgcn_sched_barrier(0);
    const int kn = s + 2;
    if (kn < nsteps) stage(kn * 32, kn % 3);
    compute(s % 3);
  }

  // Swapped C/D layout: row = l15 (+i*16), col = quad*4 + reg (+j*16).
  OutT* C = (OutT*)d.C;
  const int row0 = bm + wm + l15;
  const int col0 = bn + wn + quad * 4;
  float mn = 3.4e38f, mx = -3.4e38f;
#pragma unroll
  for (int i = 0; i < 4; ++i) {
    const long row = row0 + i * 16;
#pragma unroll
    for (int j = 0; j < NJ; ++j) {
      const int col = col0 + j * 16;
      f32x4 bv = d.bias ? *(const f32x4*)&d.bias[col] : (f32x4){0.f, 0.f, 0.f, 0.f};
      f32x4 v;
#pragma unroll
      for (int r = 0; r < 4; ++r) {
        float x = acc[i][j][r] + bv[r];
        if (d.act == 1) x = fmaxf(x, 0.f);
        else if (d.act == 2) x = 1.f / (1.f + expf(-x));
        v[r] = x;
        if (MINMAX) { mn = fminf(mn, x); mx = fmaxf(mx, x); }
      }
      if constexpr (sizeof(OutT) == 4) {
        *(f32x4*)&((float*)C)[row * N + col] = v;
      } else {
        bf16x4 o;
        o[0] = (bf16_t)v[0]; o[1] = (bf16_t)v[1];
        o[2] = (bf16_t)v[2]; o[3] = (bf16_t)v[3];
        *(bf16x4*)&((bf16_t*)C)[row * N + col] = o;
      }
    }
  }
  if (MINMAX) {
#pragma unroll
    for (int off = 32; off > 0; off >>= 1) {
      mn = fminf(mn, __shfl_down(mn, off));
      mx = fmaxf(mx, __shfl_down(mx, off));
    }
    __shared__ float smn[4], smx[4];
    if (lane == 0) { smn[wave] = mn; smx[wave] = mx; }
    __syncthreads();
    if (t == 0) {
      pmin[blockIdx.x] = fminf(fminf(smn[0], smn[1]), fminf(smn[2], smn[3]));
      pmax[blockIdx.x] = fmaxf(fmaxf(smx[0], smx[1]), fmaxf(smx[2], smx[3]));
    }
  }
}

// ---- merged projection dots: out[row] = sigmoid(dot(A[row], w) + b) ----
struct RDesc { const bf16_t* A; const float* w; const float* b; float* out; int K; };

__global__ __launch_bounds__(64) void rowdot2(RDesc d0, RDesc d1) {
  const RDesc d = blockIdx.y ? d1 : d0;
  const int row = blockIdx.x;
  const int lane = threadIdx.x;
  const bf16_t* a = d.A + (long)row * d.K;
  float s = 0.f;
  for (int k = lane * 8; k < d.K; k += 64 * 8) {
    bf16x8 av = *(const bf16x8*)&a[k];
    float4 w0 = *(const float4*)&d.w[k];
    float4 w1 = *(const float4*)&d.w[k + 4];
    s += (float)av[0] * w0.x + (float)av[1] * w0.y +
         (float)av[2] * w0.z + (float)av[3] * w0.w +
         (float)av[4] * w1.x + (float)av[5] * w1.y +
         (float)av[6] * w1.z + (float)av[7] * w1.w;
  }
#pragma unroll
  for (int off = 32; off > 0; off >>= 1) s += __shfl_down(s, off);
  if (lane == 0) d.out[row] = 1.f / (1.f + expf(-(s + d.b[0])));
}

// ---- normalize with folded final minmax reduce ----
__global__ __launch_bounds__(256) void normalize_k(
    float* __restrict__ out, const float* __restrict__ pmin,
    const float* __restrict__ pmax, int nb, long n) {
  float mn = 3.4e38f, mx = -3.4e38f;
  for (int i = threadIdx.x; i < nb; i += 256) {
    mn = fminf(mn, pmin[i]);
    mx = fmaxf(mx, pmax[i]);
  }
#pragma unroll
  for (int off = 32; off > 0; off >>= 1) {
    mn = fminf(mn, __shfl_down(mn, off));
    mx = fmaxf(mx, __shfl_down(mx, off));
  }
  __shared__ float smn[4], smx[4];
  const int wv = threadIdx.x >> 6, ln = threadIdx.x & 63;
  if (ln == 0) { smn[wv] = mn; smx[wv] = mx; }
  __syncthreads();
  mn = fminf(fminf(smn[0], smn[1]), fminf(smn[2], smn[3]));
  mx = fmaxf(fmaxf(smx[0], smx[1]), fmaxf(smx[2], smx[3]));
  const float inv = 1.f / (mx - mn);

  long i = ((long)blockIdx.x * 256 + threadIdx.x) * 4;
  const long stride = (long)gridDim.x * 256 * 4;
  for (; i < n; i += stride) {
    float4 v = *(const float4*)&out[i];
    v.x = (v.x - mn) * inv;
    v.y = (v.y - mn) * inv;
    v.z = (v.z - mn) * inv;
    v.w = (v.w - mn) * inv;
    *(float4*)&out[i] = v;
  }
}

extern "C" void kernel_launch(void* const* d_in, const int* in_sizes, int n_in,
                              void* d_out, int out_size, void* d_ws,
                              size_t ws_size, hipStream_t stream) {
  const float* x1   = (const float*)d_in[0];
  const float* x2   = (const float*)d_in[1];
  const float* W1_1 = (const float*)d_in[2];   const float* b1_1 = (const float*)d_in[3];
  const float* W1_2 = (const float*)d_in[4];   const float* b1_2 = (const float*)d_in[5];
  const float* W1_3 = (const float*)d_in[6];   const float* b1_3 = (const float*)d_in[7];
  const float* W1_4 = (const float*)d_in[8];   const float* b1_4 = (const float*)d_in[9];
  const float* W1_5 = (const float*)d_in[10];  const float* b1_5 = (const float*)d_in[11];
  const float* Wp1  = (const float*)d_in[12];  const float* bp1  = (const float*)d_in[13];
  const float* W2_1 = (const float*)d_in[14];  const float* b2_1 = (const float*)d_in[15];
  const float* W2_2 = (const float*)d_in[16];  const float* b2_2 = (const float*)d_in[17];
  const float* W2_3 = (const float*)d_in[18];  const float* b2_3 = (const float*)d_in[19];
  const float* Wp2  = (const float*)d_in[20];  const float* bp2  = (const float*)d_in[21];

  float* out = (float*)d_out;
  float* out_pre_data  = out;
  float* out_pre_dm    = out + 4096;                      // 64 MB f32
  float* out_pre_model = out + 4096 + (long)4096 * 4096;

  // 64 MB arena inside the (dead until scores) pre_dm output region.
  char* arena = (char*)out_pre_dm;
  const size_t MB = 1024 * 1024;
  bf16_t* x1b   = (bf16_t*)(arena);            // 8 MB  [4096,1024]
  bf16_t* x2b   = (bf16_t*)(arena + 8 * MB);   // 4 MB  [4096,512]
  bf16_t* W1_1b = (bf16_t*)(arena + 12 * MB);  // 4 MB
  bf16_t* W1_2b = (bf16_t*)(arena + 16 * MB);  // 4 MB
  bf16_t* W1_3b = (bf16_t*)(arena + 20 * MB);  // 1 MB
  bf16_t* W1_4b = (bf16_t*)(arena + 21 * MB);  // 1 MB
  bf16_t* W1_5b = (bf16_t*)(arena + 22 * MB);  // 4 MB
  bf16_t* W2_1b = (bf16_t*)(arena + 26 * MB);  // 1 MB
  bf16_t* W2_2b = (bf16_t*)(arena + 27 * MB);  // 1 MB
  bf16_t* W2_3b = (bf16_t*)(arena + 28 * MB);  // 1 MB
  bf16_t* bufA  = (bf16_t*)(arena + 32 * MB);  // 16 MB [4096,2048] B1 even
  bf16_t* bufB  = (bf16_t*)(arena + 48 * MB);  // 8 MB  [4096,1024] B1 odd
  bf16_t* bufC  = (bf16_t*)(arena + 56 * MB);  // 8 MB  [4096,1024] B2

  char* ws = (char*)d_ws;
  bf16_t* bufX1 = (bf16_t*)(ws);            // 4 MB [4096,512]
  bf16_t* bufX2 = (bf16_t*)(ws + 4 * MB);   // 4 MB [4096,512]
  float* pmin = (float*)(ws + 8 * MB);
  float* pmax = pmin + 2048;

  CvtArgs ca;
  ca.d[0] = {x1,   x1b,   (long)4096 * 1024};
  ca.d[1] = {x2,   x2b,   (long)4096 * 512};
  ca.d[2] = {W1_1, W1_1b, (long)2048 * 1024};
  ca.d[3] = {W1_2, W1_2b, (long)1024 * 2048};
  ca.d[4] = {W1_3, W1_3b, (long)512 * 1024};
  ca.d[5] = {W1_4, W1_4b, (long)1024 * 512};
  ca.d[6] = {W1_5, W1_5b, (long)2048 * 1024};
  ca.d[7] = {W2_1, W2_1b, (long)1024 * 512};
  ca.d[8] = {W2_2, W2_2b, (long)512 * 1024};
  ca.d[9] = {W2_3, W2_3b, (long)1024 * 512};
  cvt_many<<<dim3(192, 10), 256, 0, stream>>>(ca);

  const long nS = (long)4096 * 4096;
  GArgs g;

  // G1: B1L1 (relu) + B2L1 (relu) at BN=128 (tiles = 32 * N/128)
  g.d[0] = {x1b, W1_1b, b1_1, bufA, 2048, 1024, 1};
  g.d[1] = {x2b, W2_1b, b2_1, bufC, 1024, 512, 1};
  g.ntiles0 = 512;
  gemm_gb<bf16_t, false, 128><<<768, 256, 0, stream>>>(g, nullptr, nullptr);

  // G2: B1L2 (relu, 512) + B2L2 (sigmoid, 256) at BN=64 (tiles = 32 * N/64)
  g.d[0] = {bufA, W1_2b, b1_2, bufB, 1024, 2048, 1};
  g.d[1] = {bufC, W2_2b, b2_2, bufX2, 512, 1024, 2};
  g.ntiles0 = 512;
  gemm_gb<bf16_t, false, 64><<<768, 256, 0, stream>>>(g, nullptr, nullptr);

  // G3: B1L3 (sigmoid, 256) + B2L3 (relu, 512) at BN=64
  g.d[0] = {bufB, W1_3b, b1_3, bufX1, 512, 1024, 2};
  g.d[1] = {bufX2, W2_3b, b2_3, bufC, 1024, 512, 1};
  g.ntiles0 = 256;
  gemm_gb<bf16_t, false, 64><<<768, 256, 0, stream>>>(g, nullptr, nullptr);

  // B1L4 (relu, 512) at BN=64
  g.d[0] = {bufX1, W1_4b, b1_4, bufB, 1024, 512, 1};
  g.d[1] = g.d[0];
  g.ntiles0 = 512;
  gemm_gb<bf16_t, false, 64><<<512, 256, 0, stream>>>(g, nullptr, nullptr);

  // B1L5 (relu, 1024) at BN=64
  g.d[0] = {bufB, W1_5b, b1_5, bufA, 2048, 1024, 1};
  g.d[1] = g.d[0];
  g.ntiles0 = 1024;
  gemm_gb<bf16_t, false, 64><<<1024, 256, 0, stream>>>(g, nullptr, nullptr);

  // both projections
  RDesc r0 = {bufA, Wp1, bp1, out_pre_data, 2048};
  RDesc r1 = {bufC, Wp2, bp2, out_pre_model, 1024};
  rowdot2<<<dim3(4096, 2), 64, 0, stream>>>(r0, r1);

  // scores (f32, fused per-block min/max partials) at BN=64, grid 2048
  g.d[0] = {bufX1, bufX2, nullptr, out_pre_dm, 4096, 512, 0};
  g.d[1] = g.d[0];
  g.ntiles0 = 2048;
  gemm_gb<float, true, 64><<<2048, 256, 0, stream>>>(g, pmin, pmax);

  // normalize with folded partial-minmax reduce
  normalize_k<<<2048, 256, 0, stream>>>(out_pre_dm, pmin, pmax, 2048, nS);
}

// Round 10
// 351.806 us; speedup vs baseline: 1.0083x; 1.0083x over previous
//
#include <hip/hip_runtime.h>
#include <hip/hip_bf16.h>

typedef __bf16 bf16_t;
typedef bf16_t bf16x8 __attribute__((ext_vector_type(8)));
typedef bf16_t bf16x4 __attribute__((ext_vector_type(4)));
typedef float f32x4 __attribute__((ext_vector_type(4)));

typedef __attribute__((address_space(1))) const void gconst_void;
typedef __attribute__((address_space(3))) void lds_void;

__device__ __forceinline__ void async16(const bf16_t* g, bf16_t* l) {
  __builtin_amdgcn_global_load_lds((gconst_void*)g, (lds_void*)l, 16, 0, 0);
}

// ---- batched f32 -> bf16 conversion ----
struct CvtDesc { const float* src; bf16_t* dst; long n; };
struct CvtArgs { CvtDesc d[10]; };

__global__ __launch_bounds__(256) void cvt_many(CvtArgs a) {
  const CvtDesc de = a.d[blockIdx.y];
  long i = ((long)blockIdx.x * 256 + threadIdx.x) * 4;
  const long stride = (long)gridDim.x * 256 * 4;
  for (; i < de.n; i += stride) {
    float4 v = *(const float4*)(de.src + i);
    bf16x4 o;
    o[0] = (bf16_t)v.x; o[1] = (bf16_t)v.y; o[2] = (bf16_t)v.z; o[3] = (bf16_t)v.w;
    *(bf16x4*)(de.dst + i) = o;
  }
}

// ---- grouped GEMM: C[4096,N] = act(A[4096,K] @ W[N,K]^T + bias) ----
// Tile 128xBN (BN=64 or 128), 4 waves in 2x2, each wave owns 64x(BN/2).
// Depth-3 software pipeline: stage for step s issued at step s-2; raw
// s_barrier + counted vmcnt (never 0 in steady state). 3 LDS buffers.
// Two barriers per K-step (measured best vs 1-barrier and __syncthreads
// variants -- R8 config, 349.0 us total).
// M fixed 4096 (32 row-tiles), N mult of BN, K mult of 32 (>=4 steps).
// act: 0=none 1=relu 2=sigmoid. Up to 2 independent problems per launch.
struct GDesc {
  const bf16_t* A; const bf16_t* W; const float* bias; void* C;
  int N, K, act;
};
struct GArgs { GDesc d[2]; int ntiles0; };

template <typename OutT, bool MINMAX, int BN>
__global__ __launch_bounds__(256) void gemm_gb(GArgs ga, float* __restrict__ pmin,
                                               float* __restrict__ pmax) {
  constexpr int NJ = BN / 32;        // B-frags per wave (wave owns BN/2 cols)
  const int b = blockIdx.x;
  const int p = (b >= ga.ntiles0) ? 1 : 0;
  const GDesc d = ga.d[p];
  const int local = b - (p ? ga.ntiles0 : 0);
  const int bm = (local & 31) * 128;   // 32 row tiles (M=4096)
  const int bn = (local >> 5) * BN;
  const int N = d.N, K = d.K;

  // triple-buffered LDS tiles: BN=64 -> 36 KB, BN=128 -> 48 KB
  __shared__ __align__(16) bf16_t As[3][128 * 32];
  __shared__ __align__(16) bf16_t Bs[3][BN * 32];

  const int t = threadIdx.x;
  const int wave = t >> 6;
  const int lane = t & 63;
  const int quad = lane >> 4;
  const int l15 = lane & 15;
  const int wm = (wave >> 1) * 64;        // waves 2M x 2N
  const int wn = (wave & 1) * (BN / 2);

  f32x4 acc[4][NJ];
#pragma unroll
  for (int i = 0; i < 4; ++i)
#pragma unroll
    for (int j = 0; j < NJ; ++j) acc[i][j] = (f32x4){0.f, 0.f, 0.f, 0.f};

  // Staging swizzle: LDS slot s of row r holds global k-chunk (s-r-(r>>2))&3;
  // reader (quad q) uses slot (q+r+(r>>2))&3 (2-way worst-case aliasing).
  const int c0 = t, c1 = t + 256;
  const int r0 = c0 >> 2, kc0 = ((c0 & 3) - r0 - (r0 >> 2)) & 3;
  const int r1 = c1 >> 2, kc1 = ((c1 & 3) - r1 - (r1 >> 2)) & 3;
  const bf16_t* pa0 = d.A + (long)(bm + r0) * K + kc0 * 8;
  const bf16_t* pa1 = d.A + (long)(bm + r1) * K + kc1 * 8;
  const bf16_t* pw0 = d.W + (long)(bn + r0) * K + kc0 * 8;
  const bf16_t* pw1 = d.W + (long)(bn + r1) * K + kc1 * 8;  // BN=128 only
  bf16_t* lA0 = &As[0][c0 * 8]; bf16_t* lA1 = &As[0][c1 * 8];
  bf16_t* lB0 = &Bs[0][c0 * 8]; bf16_t* lB1 = &Bs[0][c1 * 8];
  const int bufOffA = 128 * 32;
  const int bufOffB = BN * 32;

  auto stage = [&](int ke, int bi) {
    const int oA = bi * bufOffA, oB = bi * bufOffB;
    async16(pa0 + ke, lA0 + oA);
    async16(pa1 + ke, lA1 + oA);
    async16(pw0 + ke, lB0 + oB);
    if constexpr (BN == 128) async16(pw1 + ke, lB1 + oB);
  };

  auto compute = [&](int bi) {
    const bf16_t* as = As[bi];
    const bf16_t* bs = Bs[bi];
    bf16x8 af[4], bfr[NJ];
#pragma unroll
    for (int i = 0; i < 4; ++i) {
      const int r = wm + i * 16 + l15;
      af[i] = *(const bf16x8*)&as[r * 32 + ((quad + r + (r >> 2)) & 3) * 8];
    }
#pragma unroll
    for (int j = 0; j < NJ; ++j) {
      const int r = wn + j * 16 + l15;
      bfr[j] = *(const bf16x8*)&bs[r * 32 + ((quad + r + (r >> 2)) & 3) * 8];
    }
    // Swapped operand order: register quad holds 4 consecutive output cols.
#pragma unroll
    for (int i = 0; i < 4; ++i)
#pragma unroll
      for (int j = 0; j < NJ; ++j)
        acc[i][j] = __builtin_amdgcn_mfma_f32_16x16x32_bf16(bfr[j], af[i],
                                                            acc[i][j], 0, 0, 0);
  };

  const int nsteps = K >> 5;
  stage(0, 0);
  stage(32, 1);
  int s = 0;
  for (; s < nsteps - 2; ++s) {
    __builtin_amdgcn_s_barrier();
    __builtin_amdgcn_sched_barrier(0);
    stage((s + 2) * 32, (s + 2) % 3);
    if constexpr (BN == 128)
      asm volatile("s_waitcnt vmcnt(8)" ::: "memory");
    else
      asm volatile("s_waitcnt vmcnt(6)" ::: "memory");
    __builtin_amdgcn_s_barrier();
    __builtin_amdgcn_sched_barrier(0);
    compute(s % 3);
  }
  __builtin_amdgcn_s_barrier();
  if constexpr (BN == 128)
    asm volatile("s_waitcnt vmcnt(4)" ::: "memory");
  else
    asm volatile("s_waitcnt vmcnt(3)" ::: "memory");
  __builtin_amdgcn_s_barrier();
  __builtin_amdgcn_sched_barrier(0);
  compute(s % 3);
  ++s;
  asm volatile("s_waitcnt vmcnt(0)" ::: "memory");
  __builtin_amdgcn_s_barrier();
  __builtin_amdgcn_sched_barrier(0);
  compute(s % 3);

  // Swapped C/D layout: row = l15 (+i*16), col = quad*4 + reg (+j*16).
  OutT* C = (OutT*)d.C;
  const int row0 = bm + wm + l15;
  const int col0 = bn + wn + quad * 4;
  float mn = 3.4e38f, mx = -3.4e38f;
#pragma unroll
  for (int i = 0; i < 4; ++i) {
    const long row = row0 + i * 16;
#pragma unroll
    for (int j = 0; j < NJ; ++j) {
      const int col = col0 + j * 16;
      f32x4 bv = d.bias ? *(const f32x4*)&d.bias[col] : (f32x4){0.f, 0.f, 0.f, 0.f};
      f32x4 v;
#pragma unroll
      for (int r = 0; r < 4; ++r) {
        float x = acc[i][j][r] + bv[r];
        if (d.act == 1) x = fmaxf(x, 0.f);
        else if (d.act == 2) x = 1.f / (1.f + expf(-x));
        v[r] = x;
        if (MINMAX) { mn = fminf(mn, x); mx = fmaxf(mx, x); }
      }
      if constexpr (sizeof(OutT) == 4) {
        *(f32x4*)&((float*)C)[row * N + col] = v;
      } else {
        bf16x4 o;
        o[0] = (bf16_t)v[0]; o[1] = (bf16_t)v[1];
        o[2] = (bf16_t)v[2]; o[3] = (bf16_t)v[3];
        *(bf16x4*)&((bf16_t*)C)[row * N + col] = o;
      }
    }
  }
  if (MINMAX) {
#pragma unroll
    for (int off = 32; off > 0; off >>= 1) {
      mn = fminf(mn, __shfl_down(mn, off));
      mx = fmaxf(mx, __shfl_down(mx, off));
    }
    __shared__ float smn[4], smx[4];
    if (lane == 0) { smn[wave] = mn; smx[wave] = mx; }
    __syncthreads();
    if (t == 0) {
      pmin[blockIdx.x] = fminf(fminf(smn[0], smn[1]), fminf(smn[2], smn[3]));
      pmax[blockIdx.x] = fmaxf(fmaxf(smx[0], smx[1]), fmaxf(smx[2], smx[3]));
    }
  }
}

// ---- merged projection dots: out[row] = sigmoid(dot(A[row], w) + b) ----
// 256-thread blocks, 4 rows per block (one per wave): 4x fewer blocks than
// the 64-thread version, same per-lane access pattern.
struct RDesc { const bf16_t* A; const float* w; const float* b; float* out; int K; };

__global__ __launch_bounds__(256) void rowdot2(RDesc d0, RDesc d1) {
  const RDesc d = blockIdx.y ? d1 : d0;
  const int wave = threadIdx.x >> 6;
  const int lane = threadIdx.x & 63;
  const int row = blockIdx.x * 4 + wave;
  const bf16_t* a = d.A + (long)row * d.K;
  float s = 0.f;
  for (int k = lane * 8; k < d.K; k += 64 * 8) {
    bf16x8 av = *(const bf16x8*)&a[k];
    float4 w0 = *(const float4*)&d.w[k];
    float4 w1 = *(const float4*)&d.w[k + 4];
    s += (float)av[0] * w0.x + (float)av[1] * w0.y +
         (float)av[2] * w0.z + (float)av[3] * w0.w +
         (float)av[4] * w1.x + (float)av[5] * w1.y +
         (float)av[6] * w1.z + (float)av[7] * w1.w;
  }
#pragma unroll
  for (int off = 32; off > 0; off >>= 1) s += __shfl_down(s, off);
  if (lane == 0) d.out[row] = 1.f / (1.f + expf(-(s + d.b[0])));
}

// ---- normalize with folded final minmax reduce ----
__global__ __launch_bounds__(256) void normalize_k(
    float* __restrict__ out, const float* __restrict__ pmin,
    const float* __restrict__ pmax, int nb, long n) {
  float mn = 3.4e38f, mx = -3.4e38f;
  for (int i = threadIdx.x; i < nb; i += 256) {
    mn = fminf(mn, pmin[i]);
    mx = fmaxf(mx, pmax[i]);
  }
#pragma unroll
  for (int off = 32; off > 0; off >>= 1) {
    mn = fminf(mn, __shfl_down(mn, off));
    mx = fmaxf(mx, __shfl_down(mx, off));
  }
  __shared__ float smn[4], smx[4];
  const int wv = threadIdx.x >> 6, ln = threadIdx.x & 63;
  if (ln == 0) { smn[wv] = mn; smx[wv] = mx; }
  __syncthreads();
  mn = fminf(fminf(smn[0], smn[1]), fminf(smn[2], smn[3]));
  mx = fmaxf(fmaxf(smx[0], smx[1]), fmaxf(smx[2], smx[3]));
  const float inv = 1.f / (mx - mn);

  long i = ((long)blockIdx.x * 256 + threadIdx.x) * 4;
  const long stride = (long)gridDim.x * 256 * 4;
  for (; i < n; i += stride) {
    float4 v = *(const float4*)&out[i];
    v.x = (v.x - mn) * inv;
    v.y = (v.y - mn) * inv;
    v.z = (v.z - mn) * inv;
    v.w = (v.w - mn) * inv;
    *(float4*)&out[i] = v;
  }
}

extern "C" void kernel_launch(void* const* d_in, const int* in_sizes, int n_in,
                              void* d_out, int out_size, void* d_ws,
                              size_t ws_size, hipStream_t stream) {
  const float* x1   = (const float*)d_in[0];
  const float* x2   = (const float*)d_in[1];
  const float* W1_1 = (const float*)d_in[2];   const float* b1_1 = (const float*)d_in[3];
  const float* W1_2 = (const float*)d_in[4];   const float* b1_2 = (const float*)d_in[5];
  const float* W1_3 = (const float*)d_in[6];   const float* b1_3 = (const float*)d_in[7];
  const float* W1_4 = (const float*)d_in[8];   const float* b1_4 = (const float*)d_in[9];
  const float* W1_5 = (const float*)d_in[10];  const float* b1_5 = (const float*)d_in[11];
  const float* Wp1  = (const float*)d_in[12];  const float* bp1  = (const float*)d_in[13];
  const float* W2_1 = (const float*)d_in[14];  const float* b2_1 = (const float*)d_in[15];
  const float* W2_2 = (const float*)d_in[16];  const float* b2_2 = (const float*)d_in[17];
  const float* W2_3 = (const float*)d_in[18];  const float* b2_3 = (const float*)d_in[19];
  const float* Wp2  = (const float*)d_in[20];  const float* bp2  = (const float*)d_in[21];

  float* out = (float*)d_out;
  float* out_pre_data  = out;
  float* out_pre_dm    = out + 4096;                      // 64 MB f32
  float* out_pre_model = out + 4096 + (long)4096 * 4096;

  // 64 MB arena inside the (dead until scores) pre_dm output region.
  char* arena = (char*)out_pre_dm;
  const size_t MB = 1024 * 1024;
  bf16_t* x1b   = (bf16_t*)(arena);            // 8 MB  [4096,1024]
  bf16_t* x2b   = (bf16_t*)(arena + 8 * MB);   // 4 MB  [4096,512]
  bf16_t* W1_1b = (bf16_t*)(arena + 12 * MB);  // 4 MB
  bf16_t* W1_2b = (bf16_t*)(arena + 16 * MB);  // 4 MB
  bf16_t* W1_3b = (bf16_t*)(arena + 20 * MB);  // 1 MB
  bf16_t* W1_4b = (bf16_t*)(arena + 21 * MB);  // 1 MB
  bf16_t* W1_5b = (bf16_t*)(arena + 22 * MB);  // 4 MB
  bf16_t* W2_1b = (bf16_t*)(arena + 26 * MB);  // 1 MB
  bf16_t* W2_2b = (bf16_t*)(arena + 27 * MB);  // 1 MB
  bf16_t* W2_3b = (bf16_t*)(arena + 28 * MB);  // 1 MB
  bf16_t* bufA  = (bf16_t*)(arena + 32 * MB);  // 16 MB [4096,2048] B1 even
  bf16_t* bufB  = (bf16_t*)(arena + 48 * MB);  // 8 MB  [4096,1024] B1 odd
  bf16_t* bufC  = (bf16_t*)(arena + 56 * MB);  // 8 MB  [4096,1024] B2

  char* ws = (char*)d_ws;
  bf16_t* bufX1 = (bf16_t*)(ws);            // 4 MB [4096,512]
  bf16_t* bufX2 = (bf16_t*)(ws + 4 * MB);   // 4 MB [4096,512]
  float* pmin = (float*)(ws + 8 * MB);
  float* pmax = pmin + 2048;

  CvtArgs ca;
  ca.d[0] = {x1,   x1b,   (long)4096 * 1024};
  ca.d[1] = {x2,   x2b,   (long)4096 * 512};
  ca.d[2] = {W1_1, W1_1b, (long)2048 * 1024};
  ca.d[3] = {W1_2, W1_2b, (long)1024 * 2048};
  ca.d[4] = {W1_3, W1_3b, (long)512 * 1024};
  ca.d[5] = {W1_4, W1_4b, (long)1024 * 512};
  ca.d[6] = {W1_5, W1_5b, (long)2048 * 1024};
  ca.d[7] = {W2_1, W2_1b, (long)1024 * 512};
  ca.d[8] = {W2_2, W2_2b, (long)512 * 1024};
  ca.d[9] = {W2_3, W2_3b, (long)1024 * 512};
  cvt_many<<<dim3(192, 10), 256, 0, stream>>>(ca);

  const long nS = (long)4096 * 4096;
  GArgs g;

  // G1: B1L1 (relu) + B2L1 (relu) at BN=128 (tiles = 32 * N/128)
  g.d[0] = {x1b, W1_1b, b1_1, bufA, 2048, 1024, 1};
  g.d[1] = {x2b, W2_1b, b2_1, bufC, 1024, 512, 1};
  g.ntiles0 = 512;
  gemm_gb<bf16_t, false, 128><<<768, 256, 0, stream>>>(g, nullptr, nullptr);

  // G2: B1L2 (relu, 512) + B2L2 (sigmoid, 256) at BN=64 (tiles = 32 * N/64)
  g.d[0] = {bufA, W1_2b, b1_2, bufB, 1024, 2048, 1};
  g.d[1] = {bufC, W2_2b, b2_2, bufX2, 512, 1024, 2};
  g.ntiles0 = 512;
  gemm_gb<bf16_t, false, 64><<<768, 256, 0, stream>>>(g, nullptr, nullptr);

  // G3: B1L3 (sigmoid, 256) + B2L3 (relu, 512) at BN=64
  g.d[0] = {bufB, W1_3b, b1_3, bufX1, 512, 1024, 2};
  g.d[1] = {bufX2, W2_3b, b2_3, bufC, 1024, 512, 1};
  g.ntiles0 = 256;
  gemm_gb<bf16_t, false, 64><<<768, 256, 0, stream>>>(g, nullptr, nullptr);

  // B1L4 (relu, 512) at BN=64
  g.d[0] = {bufX1, W1_4b, b1_4, bufB, 1024, 512, 1};
  g.d[1] = g.d[0];
  g.ntiles0 = 512;
  gemm_gb<bf16_t, false, 64><<<512, 256, 0, stream>>>(g, nullptr, nullptr);

  // B1L5 (relu, 1024) at BN=64
  g.d[0] = {bufB, W1_5b, b1_5, bufA, 2048, 1024, 1};
  g.d[1] = g.d[0];
  g.ntiles0 = 1024;
  gemm_gb<bf16_t, false, 64><<<1024, 256, 0, stream>>>(g, nullptr, nullptr);

  // both projections (1024 blocks x 2, 4 rows per block)
  RDesc r0 = {bufA, Wp1, bp1, out_pre_data, 2048};
  RDesc r1 = {bufC, Wp2, bp2, out_pre_model, 1024};
  rowdot2<<<dim3(1024, 2), 256, 0, stream>>>(r0, r1);

  // scores (f32, fused per-block min/max partials) at BN=64, grid 2048
  g.d[0] = {bufX1, bufX2, nullptr, out_pre_dm, 4096, 512, 0};
  g.d[1] = g.d[0];
  g.ntiles0 = 2048;
  gemm_gb<float, true, 64><<<2048, 256, 0, stream>>>(g, pmin, pmax);

  // normalize with folded partial-minmax reduce
  normalize_k<<<2048, 256, 0, stream>>>(out_pre_dm, pmin, pmax, 2048, nS);
}

// Round 11
// 340.374 us; speedup vs baseline: 1.0421x; 1.0336x over previous
//
#include <hip/hip_runtime.h>
#include <hip/hip_bf16.h>

typedef __bf16 bf16_t;
typedef bf16_t bf16x8 __attribute__((ext_vector_type(8)));
typedef bf16_t bf16x4 __attribute__((ext_vector_type(4)));
typedef float f32x4 __attribute__((ext_vector_type(4)));

typedef __attribute__((address_space(1))) const void gconst_void;
typedef __attribute__((address_space(3))) void lds_void;

__device__ __forceinline__ void async16(const bf16_t* g, bf16_t* l) {
  __builtin_amdgcn_global_load_lds((gconst_void*)g, (lds_void*)l, 16, 0, 0);
}

// ---- batched f32 -> bf16 conversion ----
struct CvtDesc { const float* src; bf16_t* dst; long n; };
struct CvtArgs { CvtDesc d[10]; };

__global__ __launch_bounds__(256) void cvt_many(CvtArgs a) {
  const CvtDesc de = a.d[blockIdx.y];
  long i = ((long)blockIdx.x * 256 + threadIdx.x) * 4;
  const long stride = (long)gridDim.x * 256 * 4;
  for (; i < de.n; i += stride) {
    float4 v = *(const float4*)(de.src + i);
    bf16x4 o;
    o[0] = (bf16_t)v.x; o[1] = (bf16_t)v.y; o[2] = (bf16_t)v.z; o[3] = (bf16_t)v.w;
    *(bf16x4*)(de.dst + i) = o;
  }
}

// ---- grouped GEMM: C[4096,N] = act(A[4096,K] @ W[N,K]^T + bias) ----
// Tile 128x64, 4 waves in 2x2, each wave owns 64x32. BK=64 (two 32-K MFMA
// groups per staged step): halves the per-K-element sync envelope (2
// barriers + vmcnt wait + LDS latency) vs BK=32.
// Depth-2 pipeline, 2 LDS buffers (48 KB -> 3 blocks/CU, same as the
// grid-limited occupancy), two barriers per step, counted vmcnt(6) in
// steady state (6 loads of stage(s+1) stay in flight at the wait).
// M fixed 4096 (32 row-tiles), N mult of 64, K mult of 64.
// act: 0=none 1=relu 2=sigmoid. Up to 2 independent problems per launch.
struct GDesc {
  const bf16_t* A; const bf16_t* W; const float* bias; void* C;
  int N, K, act;
};
struct GArgs { GDesc d[2]; int ntiles0; };

template <typename OutT, bool MINMAX>
__global__ __launch_bounds__(256) void gemm_gb(GArgs ga, float* __restrict__ pmin,
                                               float* __restrict__ pmax) {
  const int b = blockIdx.x;
  const int p = (b >= ga.ntiles0) ? 1 : 0;
  const GDesc d = ga.d[p];
  const int local = b - (p ? ga.ntiles0 : 0);
  const int bm = (local & 31) * 128;   // 32 row tiles (M=4096)
  const int bn = (local >> 5) * 64;
  const int N = d.N, K = d.K;

  // double-buffered BK=64 LDS tiles: (16 + 8) KB x 2 = 48 KB
  __shared__ __align__(16) bf16_t As[2][128 * 64];
  __shared__ __align__(16) bf16_t Bs[2][64 * 64];

  const int t = threadIdx.x;
  const int wave = t >> 6;
  const int lane = t & 63;
  const int quad = lane >> 4;
  const int l15 = lane & 15;
  const int wm = (wave >> 1) * 64;   // waves 2M x 2N
  const int wn = (wave & 1) * 32;

  f32x4 acc[4][2];
#pragma unroll
  for (int i = 0; i < 4; ++i)
#pragma unroll
    for (int j = 0; j < 2; ++j) acc[i][j] = (f32x4){0.f, 0.f, 0.f, 0.f};

  // Staging (16B chunks, 8 per row): A tile 128x64 = 1024 chunks (thread t
  // stages t, t+256, t+512, t+768); B tile 64x64 = 512 chunks (t, t+256).
  // Rotation swizzle mod 8: LDS slot s of row r holds k-chunk (s - r) & 7;
  // reader wanting k-chunk kc uses slot (kc + r) & 7. A 16-lane read phase
  // (rows r..r+15, fixed kc) spans 8 distinct slots, 2 rows/slot -> 2-way
  // bank aliasing (free, m136). Bank of a chunk depends only on its slot
  // (row stride 128 B = full bank wrap).
  const int cA0 = t, cA1 = t + 256, cA2 = t + 512, cA3 = t + 768;
  const int cB0 = t, cB1 = t + 256;
  const int rA0 = cA0 >> 3, kA0 = ((cA0 & 7) - rA0) & 7;
  const int rA1 = cA1 >> 3, kA1 = ((cA1 & 7) - rA1) & 7;
  const int rA2 = cA2 >> 3, kA2 = ((cA2 & 7) - rA2) & 7;
  const int rA3 = cA3 >> 3, kA3 = ((cA3 & 7) - rA3) & 7;
  const int rB0 = cB0 >> 3, kB0 = ((cB0 & 7) - rB0) & 7;
  const int rB1 = cB1 >> 3, kB1 = ((cB1 & 7) - rB1) & 7;
  const bf16_t* pa0 = d.A + (long)(bm + rA0) * K + kA0 * 8;
  const bf16_t* pa1 = d.A + (long)(bm + rA1) * K + kA1 * 8;
  const bf16_t* pa2 = d.A + (long)(bm + rA2) * K + kA2 * 8;
  const bf16_t* pa3 = d.A + (long)(bm + rA3) * K + kA3 * 8;
  const bf16_t* pw0 = d.W + (long)(bn + rB0) * K + kB0 * 8;
  const bf16_t* pw1 = d.W + (long)(bn + rB1) * K + kB1 * 8;
  bf16_t* lA0 = &As[0][cA0 * 8]; bf16_t* lA1 = &As[0][cA1 * 8];
  bf16_t* lA2 = &As[0][cA2 * 8]; bf16_t* lA3 = &As[0][cA3 * 8];
  bf16_t* lB0 = &Bs[0][cB0 * 8]; bf16_t* lB1 = &Bs[0][cB1 * 8];
  const int bufOffA = 128 * 64;
  const int bufOffB = 64 * 64;

  // exactly 6 global_load_lds per thread per stage (vmcnt(6) relies on it)
  auto stage = [&](int ke, int bi) {
    const int oA = bi * bufOffA, oB = bi * bufOffB;
    async16(pa0 + ke, lA0 + oA); async16(pa1 + ke, lA1 + oA);
    async16(pa2 + ke, lA2 + oA); async16(pa3 + ke, lA3 + oA);
    async16(pw0 + ke, lB0 + oB); async16(pw1 + ke, lB1 + oB);
  };

  auto compute = [&](int bi) {
    const bf16_t* as = As[bi];
    const bf16_t* bs = Bs[bi];
#pragma unroll
    for (int h = 0; h < 2; ++h) {   // two 32-K MFMA groups per step
      bf16x8 af[4], bfr[2];
#pragma unroll
      for (int i = 0; i < 4; ++i) {
        const int r = wm + i * 16 + l15;
        af[i] = *(const bf16x8*)&as[r * 64 + ((h * 4 + quad + r) & 7) * 8];
      }
#pragma unroll
      for (int j = 0; j < 2; ++j) {
        const int r = wn + j * 16 + l15;
        bfr[j] = *(const bf16x8*)&bs[r * 64 + ((h * 4 + quad + r) & 7) * 8];
      }
      // Swapped operand order: register quad holds 4 consecutive output cols.
      // acc[i][j][r] = C[wm+i*16+l15][wn+j*16+quad*4+r]
#pragma unroll
      for (int i = 0; i < 4; ++i) {
        acc[i][0] = __builtin_amdgcn_mfma_f32_16x16x32_bf16(bfr[0], af[i],
                                                            acc[i][0], 0, 0, 0);
        acc[i][1] = __builtin_amdgcn_mfma_f32_16x16x32_bf16(bfr[1], af[i],
                                                            acc[i][1], 0, 0, 0);
      }
    }
  };

  const int nsteps = K >> 6;   // K mult of 64 (min 512 -> 8 steps)
  stage(0, 0);
  for (int s = 0; s < nsteps; ++s) {
    // barrier A: all waves done READING buf[(s+1)&1] (iter s-1) before the
    // stage below overwrites it
    __builtin_amdgcn_s_barrier();
    __builtin_amdgcn_sched_barrier(0);
    const int kn = s + 1;
    if (kn < nsteps) stage(kn * 64, kn & 1);
    // wait own stage(s); stage(s+1)'s 6 loads stay in flight
    if (s == nsteps - 1)
      asm volatile("s_waitcnt vmcnt(0)" ::: "memory");
    else
      asm volatile("s_waitcnt vmcnt(6)" ::: "memory");
    // barrier B: joins -> every wave's stage(s) is complete
    __builtin_amdgcn_s_barrier();
    __builtin_amdgcn_sched_barrier(0);
    compute(s & 1);
  }

  // Swapped C/D layout: row = l15 (+i*16), col = quad*4 + reg (+j*16).
  // Each lane stores 4 consecutive f32 (16B) / 4 bf16 (8B) per (i,j).
  OutT* C = (OutT*)d.C;
  const int row0 = bm + wm + l15;
  const int col0 = bn + wn + quad * 4;
  float mn = 3.4e38f, mx = -3.4e38f;
#pragma unroll
  for (int i = 0; i < 4; ++i) {
    const long row = row0 + i * 16;
#pragma unroll
    for (int j = 0; j < 2; ++j) {
      const int col = col0 + j * 16;
      f32x4 bv = d.bias ? *(const f32x4*)&d.bias[col] : (f32x4){0.f, 0.f, 0.f, 0.f};
      f32x4 v;
#pragma unroll
      for (int r = 0; r < 4; ++r) {
        float x = acc[i][j][r] + bv[r];
        if (d.act == 1) x = fmaxf(x, 0.f);
        else if (d.act == 2) x = 1.f / (1.f + expf(-x));
        v[r] = x;
        if (MINMAX) { mn = fminf(mn, x); mx = fmaxf(mx, x); }
      }
      if constexpr (sizeof(OutT) == 4) {
        *(f32x4*)&((float*)C)[row * N + col] = v;
      } else {
        bf16x4 o;
        o[0] = (bf16_t)v[0]; o[1] = (bf16_t)v[1];
        o[2] = (bf16_t)v[2]; o[3] = (bf16_t)v[3];
        *(bf16x4*)&((bf16_t*)C)[row * N + col] = o;
      }
    }
  }
  if (MINMAX) {
#pragma unroll
    for (int off = 32; off > 0; off >>= 1) {
      mn = fminf(mn, __shfl_down(mn, off));
      mx = fmaxf(mx, __shfl_down(mx, off));
    }
    __shared__ float smn[4], smx[4];
    if (lane == 0) { smn[wave] = mn; smx[wave] = mx; }
    __syncthreads();
    if (t == 0) {
      pmin[blockIdx.x] = fminf(fminf(smn[0], smn[1]), fminf(smn[2], smn[3]));
      pmax[blockIdx.x] = fmaxf(fmaxf(smx[0], smx[1]), fmaxf(smx[2], smx[3]));
    }
  }
}

// ---- merged projection dots: out[row] = sigmoid(dot(A[row], w) + b) ----
struct RDesc { const bf16_t* A; const float* w; const float* b; float* out; int K; };

__global__ __launch_bounds__(256) void rowdot2(RDesc d0, RDesc d1) {
  const RDesc d = blockIdx.y ? d1 : d0;
  const int wave = threadIdx.x >> 6;
  const int lane = threadIdx.x & 63;
  const int row = blockIdx.x * 4 + wave;
  const bf16_t* a = d.A + (long)row * d.K;
  float s = 0.f;
  for (int k = lane * 8; k < d.K; k += 64 * 8) {
    bf16x8 av = *(const bf16x8*)&a[k];
    float4 w0 = *(const float4*)&d.w[k];
    float4 w1 = *(const float4*)&d.w[k + 4];
    s += (float)av[0] * w0.x + (float)av[1] * w0.y +
         (float)av[2] * w0.z + (float)av[3] * w0.w +
         (float)av[4] * w1.x + (float)av[5] * w1.y +
         (float)av[6] * w1.z + (float)av[7] * w1.w;
  }
#pragma unroll
  for (int off = 32; off > 0; off >>= 1) s += __shfl_down(s, off);
  if (lane == 0) d.out[row] = 1.f / (1.f + expf(-(s + d.b[0])));
}

// ---- normalize with folded final minmax reduce ----
__global__ __launch_bounds__(256) void normalize_k(
    float* __restrict__ out, const float* __restrict__ pmin,
    const float* __restrict__ pmax, int nb, long n) {
  float mn = 3.4e38f, mx = -3.4e38f;
  for (int i = threadIdx.x; i < nb; i += 256) {
    mn = fminf(mn, pmin[i]);
    mx = fmaxf(mx, pmax[i]);
  }
#pragma unroll
  for (int off = 32; off > 0; off >>= 1) {
    mn = fminf(mn, __shfl_down(mn, off));
    mx = fmaxf(mx, __shfl_down(mx, off));
  }
  __shared__ float smn[4], smx[4];
  const int wv = threadIdx.x >> 6, ln = threadIdx.x & 63;
  if (ln == 0) { smn[wv] = mn; smx[wv] = mx; }
  __syncthreads();
  mn = fminf(fminf(smn[0], smn[1]), fminf(smn[2], smn[3]));
  mx = fmaxf(fmaxf(smx[0], smx[1]), fmaxf(smx[2], smx[3]));
  const float inv = 1.f / (mx - mn);

  long i = ((long)blockIdx.x * 256 + threadIdx.x) * 4;
  const long stride = (long)gridDim.x * 256 * 4;
  for (; i < n; i += stride) {
    float4 v = *(const float4*)&out[i];
    v.x = (v.x - mn) * inv;
    v.y = (v.y - mn) * inv;
    v.z = (v.z - mn) * inv;
    v.w = (v.w - mn) * inv;
    *(float4*)&out[i] = v;
  }
}

extern "C" void kernel_launch(void* const* d_in, const int* in_sizes, int n_in,
                              void* d_out, int out_size, void* d_ws,
                              size_t ws_size, hipStream_t stream) {
  const float* x1   = (const float*)d_in[0];
  const float* x2   = (const float*)d_in[1];
  const float* W1_1 = (const float*)d_in[2];   const float* b1_1 = (const float*)d_in[3];
  const float* W1_2 = (const float*)d_in[4];   const float* b1_2 = (const float*)d_in[5];
  const float* W1_3 = (const float*)d_in[6];   const float* b1_3 = (const float*)d_in[7];
  const float* W1_4 = (const float*)d_in[8];   const float* b1_4 = (const float*)d_in[9];
  const float* W1_5 = (const float*)d_in[10];  const float* b1_5 = (const float*)d_in[11];
  const float* Wp1  = (const float*)d_in[12];  const float* bp1  = (const float*)d_in[13];
  const float* W2_1 = (const float*)d_in[14];  const float* b2_1 = (const float*)d_in[15];
  const float* W2_2 = (const float*)d_in[16];  const float* b2_2 = (const float*)d_in[17];
  const float* W2_3 = (const float*)d_in[18];  const float* b2_3 = (const float*)d_in[19];
  const float* Wp2  = (const float*)d_in[20];  const float* bp2  = (const float*)d_in[21];

  float* out = (float*)d_out;
  float* out_pre_data  = out;
  float* out_pre_dm    = out + 4096;                      // 64 MB f32
  float* out_pre_model = out + 4096 + (long)4096 * 4096;

  // 64 MB arena inside the (dead until scores) pre_dm output region.
  char* arena = (char*)out_pre_dm;
  const size_t MB = 1024 * 1024;
  bf16_t* x1b   = (bf16_t*)(arena);            // 8 MB  [4096,1024]
  bf16_t* x2b   = (bf16_t*)(arena + 8 * MB);   // 4 MB  [4096,512]
  bf16_t* W1_1b = (bf16_t*)(arena + 12 * MB);  // 4 MB
  bf16_t* W1_2b = (bf16_t*)(arena + 16 * MB);  // 4 MB
  bf16_t* W1_3b = (bf16_t*)(arena + 20 * MB);  // 1 MB
  bf16_t* W1_4b = (bf16_t*)(arena + 21 * MB);  // 1 MB
  bf16_t* W1_5b = (bf16_t*)(arena + 22 * MB);  // 4 MB
  bf16_t* W2_1b = (bf16_t*)(arena + 26 * MB);  // 1 MB
  bf16_t* W2_2b = (bf16_t*)(arena + 27 * MB);  // 1 MB
  bf16_t* W2_3b = (bf16_t*)(arena + 28 * MB);  // 1 MB
  bf16_t* bufA  = (bf16_t*)(arena + 32 * MB);  // 16 MB [4096,2048] B1 even
  bf16_t* bufB  = (bf16_t*)(arena + 48 * MB);  // 8 MB  [4096,1024] B1 odd
  bf16_t* bufC  = (bf16_t*)(arena + 56 * MB);  // 8 MB  [4096,1024] B2

  char* ws = (char*)d_ws;
  bf16_t* bufX1 = (bf16_t*)(ws);            // 4 MB [4096,512]
  bf16_t* bufX2 = (bf16_t*)(ws + 4 * MB);   // 4 MB [4096,512]
  float* pmin = (float*)(ws + 8 * MB);
  float* pmax = pmin + 2048;

  CvtArgs ca;
  ca.d[0] = {x1,   x1b,   (long)4096 * 1024};
  ca.d[1] = {x2,   x2b,   (long)4096 * 512};
  ca.d[2] = {W1_1, W1_1b, (long)2048 * 1024};
  ca.d[3] = {W1_2, W1_2b, (long)1024 * 2048};
  ca.d[4] = {W1_3, W1_3b, (long)512 * 1024};
  ca.d[5] = {W1_4, W1_4b, (long)1024 * 512};
  ca.d[6] = {W1_5, W1_5b, (long)2048 * 1024};
  ca.d[7] = {W2_1, W2_1b, (long)1024 * 512};
  ca.d[8] = {W2_2, W2_2b, (long)512 * 1024};
  ca.d[9] = {W2_3, W2_3b, (long)1024 * 512};
  cvt_many<<<dim3(192, 10), 256, 0, stream>>>(ca);

  const long nS = (long)4096 * 4096;
  GArgs g;

  // Tiles per problem = 32 * (N/64).
  // G1: B1L1 (relu, 1024) + B2L1 (relu, 512)
  g.d[0] = {x1b, W1_1b, b1_1, bufA, 2048, 1024, 1};
  g.d[1] = {x2b, W2_1b, b2_1, bufC, 1024, 512, 1};
  g.ntiles0 = 1024;
  gemm_gb<bf16_t, false><<<1536, 256, 0, stream>>>(g, nullptr, nullptr);

  // G2: B1L2 (relu, 512) + B2L2 (sigmoid, 256)
  g.d[0] = {bufA, W1_2b, b1_2, bufB, 1024, 2048, 1};
  g.d[1] = {bufC, W2_2b, b2_2, bufX2, 512, 1024, 2};
  g.ntiles0 = 512;
  gemm_gb<bf16_t, false><<<768, 256, 0, stream>>>(g, nullptr, nullptr);

  // G3: B1L3 (sigmoid, 256) + B2L3 (relu, 512)
  g.d[0] = {bufB, W1_3b, b1_3, bufX1, 512, 1024, 2};
  g.d[1] = {bufX2, W2_3b, b2_3, bufC, 1024, 512, 1};
  g.ntiles0 = 256;
  gemm_gb<bf16_t, false><<<768, 256, 0, stream>>>(g, nullptr, nullptr);

  // B1L4 (relu, 512)
  g.d[0] = {bufX1, W1_4b, b1_4, bufB, 1024, 512, 1};
  g.d[1] = g.d[0];
  g.ntiles0 = 512;
  gemm_gb<bf16_t, false><<<512, 256, 0, stream>>>(g, nullptr, nullptr);

  // B1L5 (relu, 1024)
  g.d[0] = {bufB, W1_5b, b1_5, bufA, 2048, 1024, 1};
  g.d[1] = g.d[0];
  g.ntiles0 = 1024;
  gemm_gb<bf16_t, false><<<1024, 256, 0, stream>>>(g, nullptr, nullptr);

  // both projections (1024 blocks x 2, 4 rows per block)
  RDesc r0 = {bufA, Wp1, bp1, out_pre_data, 2048};
  RDesc r1 = {bufC, Wp2, bp2, out_pre_model, 1024};
  rowdot2<<<dim3(1024, 2), 256, 0, stream>>>(r0, r1);

  // scores (f32, fused per-block min/max partials), grid 2048
  g.d[0] = {bufX1, bufX2, nullptr, out_pre_dm, 4096, 512, 0};
  g.d[1] = g.d[0];
  g.ntiles0 = 2048;
  gemm_gb<float, true><<<2048, 256, 0, stream>>>(g, pmin, pmax);

  // normalize with folded partial-minmax reduce
  normalize_k<<<2048, 256, 0, stream>>>(out_pre_dm, pmin, pmax, 2048, nS);
}